// Round 11
// baseline (456.360 us; speedup 1.0000x reference)
//
#include <hip/hip_runtime.h>
#include <hip/hip_bf16.h>

#define B_ 8
#define C_ 64
#define N_ 4096
#define K_ 20
#define O_ 64

typedef unsigned short ushort_t;
typedef __attribute__((ext_vector_type(8))) short bf16x8;
typedef __attribute__((ext_vector_type(16))) float f32x16;

constexpr float BN_EPS = 1e-5f;
constexpr float NEG = 0.2f;
constexpr int ROWS = B_ * N_;        // 32768
constexpr int M_TOT = ROWS * K_;     // 655360

__device__ __forceinline__ float readlane_f(float v, int src) {
  return __int_as_float(__builtin_amdgcn_readlane(__float_as_int(v), src));
}

// RNE float -> bf16 bits
__device__ __forceinline__ unsigned int bf16_rne(float v) {
  unsigned int u = __float_as_uint(v);
  return (u + 0x7FFFu + ((u >> 16) & 1u)) >> 16;
}

// ----------------------------------------------------------------------------
// ws layout (float elements):
//   y   : [0,        2097152)   y[b][n][o]  = xt[b,n,:] . W1[o,:]
//   z   : [2097152,  4194304)   z[b][n][o]  = xt[b,n,:] . (W2-W1)[o,:]
//   xx  : [4194304,  4227072)   xx[b][n]    = ||xt[b,n,:]||^2
//   idx : [4227072,  4882432)   (int) idx[b][n][k]
//   s1/s2 : [4882432, 4882560)
//   xfh : [4882688,  5931264)   bf16 FRAGMENT-ORDER tiles, high split
//   xfl : [5931264,  6979840)   mid split
//   xfq : [6979840,  8028416)   low split
//   hmax: [4882688,  6979840)   (overlays xfh+xfl — fragments dead after knn)
//   hmin: [6979840,  9076992)   (overlays xfq + 4 MB fresh)
// Fragment-order => MFMA A/B loads are lane-contiguous: addr = tile*2048
//   + cc*512 + lane*8 (one dwordx4 = 1 KB dense per wave).
// ----------------------------------------------------------------------------

__global__ __launch_bounds__(256) void prep_kernel(const float* __restrict__ x,
                                                   const float* __restrict__ W,
                                                   float* __restrict__ y,
                                                   float* __restrict__ z,
                                                   float* __restrict__ xx,
                                                   ushort_t* __restrict__ xfh,
                                                   ushort_t* __restrict__ xfl,
                                                   ushort_t* __restrict__ xfq) {
  __shared__ float xt[64][65];  // [n_local][c]
  __shared__ float w1[64][65];  // [o][c]   = W[o][c]
  __shared__ float wd[64][65];  // [o][c]   = W[o][64+c] - W[o][c]
  const int b = blockIdx.x >> 6;
  const int n0 = (blockIdx.x & 63) << 6;
  const int tid = threadIdx.x;

  for (int rep = 0; rep < 16; ++rep) {
    int id = rep * 256 + tid;
    int cc = id >> 6, nl = id & 63;
    xt[nl][cc] = x[((b * 64 + cc) << 12) + n0 + nl];  // coalesced over nl
    int o = cc, c = nl;
    float a = W[o * 128 + c];
    float bb = W[o * 128 + 64 + c];
    w1[o][c] = a;
    wd[o][c] = bb - a;
  }
  __syncthreads();

  const int o = tid & 63;
  for (int nl = tid >> 6; nl < 64; nl += 4) {
    float ay = 0.f, az = 0.f;
#pragma unroll 8
    for (int c = 0; c < 64; ++c) {
      float v = xt[nl][c];
      ay = fmaf(v, w1[o][c], ay);
      az = fmaf(v, wd[o][c], az);
    }
    int gi = (((b << 12) + n0 + nl) << 6) + o;
    y[gi] = ay;
    z[gi] = az;
  }
  if (tid < 64) {
    float s = 0.f;
#pragma unroll 8
    for (int c = 0; c < 64; ++c) {
      float v = xt[tid][c];
      s = fmaf(v, v, s);
    }
    xx[(b << 12) + tid + n0] = s;
  }

  // 3-way bf16 split, written in MFMA fragment order (tile/chunk/m/t)
  for (int rep = 0; rep < 16; ++rep) {
    int id = rep * 256 + tid;
    int nl = id >> 6, c = id & 63;
    float v = xt[nl][c];
    unsigned int hb = bf16_rne(v);
    float hf = __uint_as_float(hb << 16);
    float r1 = v - hf;
    unsigned int lb = bf16_rne(r1);
    float lf = __uint_as_float(lb << 16);
    unsigned int qb = bf16_rne(r1 - lf);
    const int n = n0 + nl;
    const size_t addr = ((size_t)((b << 7) + (n >> 5))) * 2048  // tile
                        + ((c >> 3) << 8)                        // chunk*256
                        + ((n & 31) << 3)                        // m*8
                        + (c & 7);                               // t
    xfh[addr] = (ushort_t)hb;
    xfl[addr] = (ushort_t)lb;
    xfq[addr] = (ushort_t)qb;
  }
}

// knn v28. R9/R10 post-mortem + m69: HW register allocation is QUANTIZED at
// 64 regs/wave (steps 64/128/256). This kernel at 60 arch + 16 acc = 76 regs
// -> quantum 128 -> hard max 4 waves/SIMD (what v21 already has); both
// launch-bounds attempts spilled because 76 > 64. v28 makes the kernel FIT
// the 64 quantum: the 48 persistent A-fragment VGPRs are replaced by
// CHUNK-RELOADS inside the cc loop (A is 12 KB/block, L1-resident, 8 waves
// share it). Peak regs ~ 24 transient A/B + 16 acc + 12 lists + addr ~= 60
// <= 64, declared via __launch_bounds__(512, 8). Single-buffer 32 KiB Dld +
// trailing barrier (v25 structure) then admits 3-4 blocks/CU = 6-8 waves/SIMD
// (R9 proved 3 blocks resident) — the clean occupancy test at last.
// A-reload cost: 3 extra L1-hit loads per cc, hidden by the extra waves.
// Selection body byte-identical to v21 (verified best, knn=291us).
__global__ __launch_bounds__(512, 8) void knn_kernel(const ushort_t* __restrict__ xfh,
                                                     const ushort_t* __restrict__ xfl,
                                                     const ushort_t* __restrict__ xfq,
                                                     const float* __restrict__ xx,
                                                     int* __restrict__ idx) {
  const int tid = threadIdx.x;
  const int w = tid >> 6;                 // wave 0..7
  const int lane = tid & 63;
  // XCD swizzle: 1024 blocks = 8 batches x 128 strips; hw round-robins
  // blockIdx%8 -> XCD, so XCD x gets wg in [x*128, (x+1)*128) = batch x.
  const int wg = ((blockIdx.x & 7) << 7) | (blockIdx.x >> 3);
  const int b = wg >> 7;                  // 128 strips per batch
  const int i0 = (wg & 127) << 5;         // 32-row strip
  const int mcol = lane & 31;
  const int half = lane >> 5;             // 0..1 (k-half)

  __shared__ float Dld[32 * 256];         // SINGLE buffer [row][256 j]

  const size_t atile = ((size_t)wg) * 2048;  // tile = b*128 + strip

  float bv[4], T[4];
  int bi[4];
#pragma unroll
  for (int r = 0; r < 4; ++r) {
    bv[r] = __builtin_inff();
    T[r] = __builtin_inff();
    bi[r] = 0;
  }

  const float* xxb = xx + (b << 12);

  for (int t = 0; t < 16; ++t) {
    const int jb = t << 8;                // 256 j per iteration
    // this wave's 32-j tile: tile index (b*128 + t*8 + w)
    const size_t btile = ((size_t)((b << 7) + (t << 3) + w)) * 2048;
    f32x16 acc;
#pragma unroll
    for (int q = 0; q < 16; ++q) acc[q] = 0.f;
#pragma unroll
    for (int cc = 0; cc < 4; ++cc) {
      // chunked A reload (L1-hit): transient 24 VGPRs instead of 48 resident
      const size_t aoff = atile + (cc << 9) + (lane << 3);
      const size_t boff = btile + (cc << 9) + (lane << 3);
      bf16x8 Ah = *(const bf16x8*)(xfh + aoff);
      bf16x8 Bh = *(const bf16x8*)(xfh + boff);
      bf16x8 Al = *(const bf16x8*)(xfl + aoff);
      bf16x8 Bl = *(const bf16x8*)(xfl + boff);
      bf16x8 Aq = *(const bf16x8*)(xfq + aoff);
      bf16x8 Bq = *(const bf16x8*)(xfq + boff);
      acc = __builtin_amdgcn_mfma_f32_32x32x16_bf16(Ah, Bh, acc, 0, 0, 0);
      acc = __builtin_amdgcn_mfma_f32_32x32x16_bf16(Ah, Bl, acc, 0, 0, 0);
      acc = __builtin_amdgcn_mfma_f32_32x32x16_bf16(Al, Bh, acc, 0, 0, 0);
      acc = __builtin_amdgcn_mfma_f32_32x32x16_bf16(Ah, Bq, acc, 0, 0, 0);
      acc = __builtin_amdgcn_mfma_f32_32x32x16_bf16(Aq, Bh, acc, 0, 0, 0);
      acc = __builtin_amdgcn_mfma_f32_32x32x16_bf16(Al, Bl, acc, 0, 0, 0);
    }
    const float xxv = xxb[jb + (w << 5) + mcol];
#pragma unroll
    for (int q = 0; q < 16; ++q) {
      int row = (q & 3) + ((q >> 2) << 3) + (half << 2);  // verified C layout
      Dld[(row << 8) + (w << 5) + mcol] = fmaf(-2.f, acc[q], xxv);
    }
    __syncthreads();

    // selection: wave owns rows w*4 .. w*4+3, scans 256 j in four 64-lane segs
    // (byte-identical to v21)
#pragma unroll
    for (int r = 0; r < 4; ++r) {
      const int row = (w << 2) + r;
#pragma unroll
      for (int seg = 0; seg < 4; ++seg) {
        float v = Dld[(row << 8) + (seg << 6) + lane];
        const int jseg = jb + (seg << 6);
        if (T[r] == __builtin_inff()) {
          // fill phase: exact v17 live-T loop (first segment of each row)
          const int jlane = jseg + lane;
          unsigned long long rem = 0xFFFFFFFFFFFFFFFFull;
          while (true) {
            unsigned long long m = __ballot(v < T[r]) & rem;
            if (!m) break;
            int src = __ffsll(m) - 1;
            rem &= ~(1ull << src);
            float cv = readlane_f(v, src);
            int cj = __builtin_amdgcn_readlane(jlane, src);
            unsigned long long le = __ballot(bv[r] <= cv) & 0xFFFFFull;
            int pos = __popcll(le);
            float pv = __shfl_up(bv[r], 1);
            int pi = __shfl_up(bi[r], 1);
            if (lane >= pos) {
              bool ins = (lane == pos);
              bv[r] = ins ? cv : pv;
              bi[r] = ins ? cj : pi;
            }
            T[r] = readlane_f(bv[r], K_ - 1);
          }
        } else {
          // steady state: ONE stale-T filter ballot, then insert-only chain
          unsigned long long m = __ballot(v < T[r]);
          while (m) {
            const int src = __ffsll(m) - 1;
            m &= m - 1;
            const float cv = readlane_f(v, src);
            const int cj = jseg + src;  // SALU, exact
            const unsigned long long le = __ballot(bv[r] <= cv) & 0xFFFFFull;
            const int pos = __popcll(le);
            const float pv = __shfl_up(bv[r], 1);
            const int pi = __shfl_up(bi[r], 1);
            if (lane >= pos) {
              const bool ins = (lane == pos);
              bv[r] = ins ? cv : pv;
              bi[r] = ins ? cj : pi;
            }
          }
          T[r] = readlane_f(bv[r], K_ - 1);  // refresh once per segment
        }
      }
    }
    // trailing barrier: single-buffer Dld — next tile's writes must wait for
    // all waves' reads of this tile (cost traded for 3-4 blocks/CU residency).
    __syncthreads();
  }

#pragma unroll
  for (int r = 0; r < 4; ++r) {
    if (lane < K_) idx[((b << 12) + i0 + (w << 2) + r) * K_ + lane] = bi[r];
  }
}

// stats v2: same gather as before, but additionally emits per-(row,o) max/min
// of h over the K neighbors. Since hn = s*h + t is affine and LeakyReLU is
// monotone, out only needs max_k h (s>=0) or min_k h (s<0) — bitwise equal to
// max_k act(fma(h_k,s,t)) because fma and act are monotone in h.
__global__ __launch_bounds__(256) void stats_kernel(const float* __restrict__ y,
                                                    const float* __restrict__ z,
                                                    const int* __restrict__ idx,
                                                    float* __restrict__ s1,
                                                    float* __restrict__ s2,
                                                    float* __restrict__ hmax,
                                                    float* __restrict__ hmin) {
  const int tid = threadIdx.x;
  const int o = tid & 63;
  const int r = tid >> 6;
  // XCD swizzle: 512 blocks = 8 batches x 64 row-groups; pin batch -> XCD so
  // each XCD's L2 holds one batch's 1 MB y panel for the gather.
  const int wg = ((blockIdx.x & 7) << 6) | (blockIdx.x >> 3);
  const int row0 = wg << 6;  // 64 rows per block
  float a1 = 0.f, a2 = 0.f;
  for (int rl = r; rl < 64; rl += 4) {
    const int row = row0 + rl;
    const int b = row >> 12;
    const float zv = z[(row << 6) + o];
    const int* ip = idx + row * K_;
    const float* yb = y + ((size_t)b << 18);
    float s1r = 0.f;
    float hmx = -__builtin_inff();
    float hmn = __builtin_inff();
#pragma unroll
    for (int k = 0; k < K_; ++k) {
      int j = ip[k];
      float h = yb[(j << 6) + o] + zv;
      s1r += h;
      a2 = fmaf(h, h, a2);
      hmx = fmaxf(hmx, h);
      hmn = fminf(hmn, h);
    }
    a1 += s1r;
    hmax[(row << 6) + o] = hmx;
    hmin[(row << 6) + o] = hmn;
  }
  __shared__ float r1[4][64];
  __shared__ float r2[4][64];
  r1[r][o] = a1;
  r2[r][o] = a2;
  __syncthreads();
  if (tid < 64) {
    float t1 = r1[0][tid] + r1[1][tid] + r1[2][tid] + r1[3][tid];
    float t2 = r2[0][tid] + r2[1][tid] + r2[2][tid] + r2[3][tid];
    atomicAdd(&s1[tid], t1);
    atomicAdd(&s2[tid], t2);
  }
}

// out v2: pure elementwise. Recomputes the (64-wide) BN affine from s1/s2
// inline, applies act to the pre-reduced extremum, transposes via LDS to the
// [B,O,N] layout. 16 MB in / 8 MB out.
__global__ __launch_bounds__(256) void out_kernel(const float* __restrict__ hmax,
                                                  const float* __restrict__ hmin,
                                                  const float* __restrict__ s1,
                                                  const float* __restrict__ s2,
                                                  const float* __restrict__ gamma,
                                                  const float* __restrict__ beta,
                                                  float* __restrict__ out) {
  __shared__ float til[64][65];  // [o][n_local]
  const int tid = threadIdx.x;
  const int b = blockIdx.x >> 6;
  const int n0 = (blockIdx.x & 63) << 6;
  const int o = tid & 63;
  // same ops as the old finalize_kernel (division kept for identical rounding)
  const float mean = s1[o] / (float)M_TOT;
  const float var = s2[o] / (float)M_TOT - mean * mean;
  const float inv = 1.0f / sqrtf(var + BN_EPS);
  const float s = gamma[o] * inv;
  const float t = beta[o] - mean * s;
  const float* __restrict__ hsrc = (s >= 0.f) ? hmax : hmin;

  for (int nl = tid >> 6; nl < 64; nl += 4) {
    const int row = (b << 12) + n0 + nl;
    const float h = hsrc[(row << 6) + o];
    const float hn = fmaf(h, s, t);
    til[o][nl] = hn >= 0.f ? hn : NEG * hn;
  }
  __syncthreads();
  for (int rep = 0; rep < 16; ++rep) {
    int id = rep * 256 + tid;
    int oo = id >> 6, nl = id & 63;
    out[((size_t)((b << 6) + oo) << 12) + n0 + nl] = til[oo][nl];
  }
}

extern "C" void kernel_launch(void* const* d_in, const int* in_sizes, int n_in,
                              void* d_out, int out_size, void* d_ws, size_t ws_size,
                              hipStream_t stream) {
  const float* x = (const float*)d_in[0];
  const float* W = (const float*)d_in[1];
  const float* gamma = (const float*)d_in[2];
  const float* beta = (const float*)d_in[3];
  float* ws = (float*)d_ws;
  float* y = ws;
  float* z = ws + 2097152;
  float* xx = ws + 4194304;
  int* idxp = (int*)(ws + 4227072);
  float* s1 = ws + 4882432;
  float* s2 = ws + 4882496;
  ushort_t* xfh = (ushort_t*)(ws + 4882688);
  ushort_t* xfl = (ushort_t*)(ws + 5931264);
  ushort_t* xfq = (ushort_t*)(ws + 6979840);
  float* hmax = ws + 4882688;  // overlays xfh+xfl (dead after knn)
  float* hmin = ws + 6979840;  // overlays xfq + 4 MB fresh (ends 9076992)
  float* out = (float*)d_out;

  hipMemsetAsync(s1, 0, 2 * 64 * sizeof(float), stream);

  prep_kernel<<<512, 256, 0, stream>>>(x, W, y, z, xx, xfh, xfl, xfq);
  knn_kernel<<<ROWS / 32, 512, 0, stream>>>(xfh, xfl, xfq, xx, idxp);
  stats_kernel<<<512, 256, 0, stream>>>(y, z, idxp, s1, s2, hmax, hmin);
  out_kernel<<<512, 256, 0, stream>>>(hmax, hmin, s1, s2, gamma, beta, out);
}

// Round 13
// 393.762 us; speedup vs baseline: 1.1590x; 1.1590x over previous
//
#include <hip/hip_runtime.h>
#include <hip/hip_bf16.h>

#define B_ 8
#define C_ 64
#define N_ 4096
#define K_ 20
#define O_ 64

typedef unsigned short ushort_t;
typedef __attribute__((ext_vector_type(8))) short bf16x8;
typedef __attribute__((ext_vector_type(16))) float f32x16;
typedef __attribute__((ext_vector_type(4))) float f32x4;

constexpr float BN_EPS = 1e-5f;
constexpr float NEG = 0.2f;
constexpr int ROWS = B_ * N_;        // 32768
constexpr int M_TOT = ROWS * K_;     // 655360

__device__ __forceinline__ float readlane_f(float v, int src) {
  return __int_as_float(__builtin_amdgcn_readlane(__float_as_int(v), src));
}

// RNE float -> bf16 bits
__device__ __forceinline__ unsigned int bf16_rne(float v) {
  unsigned int u = __float_as_uint(v);
  return (u + 0x7FFFu + ((u >> 16) & 1u)) >> 16;
}

// ----------------------------------------------------------------------------
// ws layout (float elements):
//   y   : [0,        2097152)   y[b][n][o]  = xt[b,n,:] . W1[o,:]
//   z   : [2097152,  4194304)   z[b][n][o]  = xt[b,n,:] . (W2-W1)[o,:]
//   xx  : [4194304,  4227072)   xx[b][n]    = ||xt[b,n,:]||^2
//   idx : [4227072,  4882432)   (int) idx[b][n][k]
//   s1/s2 : [4882432, 4882560)
//   xfh : [4882688,  5931264)   bf16 FRAGMENT-ORDER tiles, high split
//   xfl : [5931264,  6979840)   mid split
//   xfq : [6979840,  8028416)   low split
//   hmax: [4882688,  6979840)   (overlays xfh+xfl — fragments dead after knn)
//   hmin: [6979840,  9076992)   (overlays xfq + 4 MB fresh)
// Fragment-order => MFMA A/B loads are lane-contiguous: addr = tile*2048
//   + cc*512 + lane*8 (one dwordx4 = 1 KB dense per wave).
// ----------------------------------------------------------------------------

__global__ __launch_bounds__(256) void prep_kernel(const float* __restrict__ x,
                                                   const float* __restrict__ W,
                                                   float* __restrict__ y,
                                                   float* __restrict__ z,
                                                   float* __restrict__ xx,
                                                   ushort_t* __restrict__ xfh,
                                                   ushort_t* __restrict__ xfl,
                                                   ushort_t* __restrict__ xfq) {
  __shared__ float xt[64][65];  // [n_local][c]
  __shared__ float w1[64][65];  // [o][c]   = W[o][c]
  __shared__ float wd[64][65];  // [o][c]   = W[o][64+c] - W[o][c]
  const int b = blockIdx.x >> 6;
  const int n0 = (blockIdx.x & 63) << 6;
  const int tid = threadIdx.x;

  for (int rep = 0; rep < 16; ++rep) {
    int id = rep * 256 + tid;
    int cc = id >> 6, nl = id & 63;
    xt[nl][cc] = x[((b * 64 + cc) << 12) + n0 + nl];  // coalesced over nl
    int o = cc, c = nl;
    float a = W[o * 128 + c];
    float bb = W[o * 128 + 64 + c];
    w1[o][c] = a;
    wd[o][c] = bb - a;
  }
  __syncthreads();

  const int o = tid & 63;
  for (int nl = tid >> 6; nl < 64; nl += 4) {
    float ay = 0.f, az = 0.f;
#pragma unroll 8
    for (int c = 0; c < 64; ++c) {
      float v = xt[nl][c];
      ay = fmaf(v, w1[o][c], ay);
      az = fmaf(v, wd[o][c], az);
    }
    int gi = (((b << 12) + n0 + nl) << 6) + o;
    y[gi] = ay;
    z[gi] = az;
  }
  if (tid < 64) {
    float s = 0.f;
#pragma unroll 8
    for (int c = 0; c < 64; ++c) {
      float v = xt[tid][c];
      s = fmaf(v, v, s);
    }
    xx[(b << 12) + tid + n0] = s;
  }

  // 3-way bf16 split, written in MFMA fragment order (tile/chunk/m/t)
  for (int rep = 0; rep < 16; ++rep) {
    int id = rep * 256 + tid;
    int nl = id >> 6, c = id & 63;
    float v = xt[nl][c];
    unsigned int hb = bf16_rne(v);
    float hf = __uint_as_float(hb << 16);
    float r1 = v - hf;
    unsigned int lb = bf16_rne(r1);
    float lf = __uint_as_float(lb << 16);
    unsigned int qb = bf16_rne(r1 - lf);
    const int n = n0 + nl;
    const size_t addr = ((size_t)((b << 7) + (n >> 5))) * 2048  // tile
                        + ((c >> 3) << 8)                        // chunk*256
                        + ((n & 31) << 3)                        // m*8
                        + (c & 7);                               // t
    xfh[addr] = (ushort_t)hb;
    xfl[addr] = (ushort_t)lb;
    xfq[addr] = (ushort_t)qb;
  }
}

// knn v30 = v21 (verified best, knn=291us; R9-R11 proved the 64-reg quantum
// is unreachable -> occupancy axis closed, back to (512,2) dbuf structure)
// with two EXACT overhead removals in selection:
//  (a) b128 SEGMENT READS via swizzled Dld: column c of the 256-wide tile is
//      stored at float-offset ((c&63)<<2)|(c>>6), so ONE ds_read_b128 per
//      (row,tile) hands lane l columns {l, 64+l, 128+l, 192+l} = all 256
//      candidates. Processing subs s=0..3 ascending (j = jb+s*64+lane, ffs
//      ascending lane) preserves the exact ascending-j candidate order ->
//      selection bitwise-identical to v21 (incl. fill = sub 0 of tile 0).
//      Replaces 4 b32 reads + addr calcs per row-tile; 4x less exposed LDS
//      latency. Write banks go 2->4-way on 16 stores/tile (negligible).
//  (b) GUARDED T-refresh: T changes only if an insert happened; skip the
//      trailing readlane when the segment mask is empty (most late segments).
// (Resubmitted unchanged: R12 bench was an infra failure, no data.)
__global__ __launch_bounds__(512, 2) void knn_kernel(const ushort_t* __restrict__ xfh,
                                                     const ushort_t* __restrict__ xfl,
                                                     const ushort_t* __restrict__ xfq,
                                                     const float* __restrict__ xx,
                                                     int* __restrict__ idx) {
  const int tid = threadIdx.x;
  const int w = tid >> 6;                 // wave 0..7
  const int lane = tid & 63;
  // XCD swizzle: 1024 blocks = 8 batches x 128 strips; hw round-robins
  // blockIdx%8 -> XCD, so XCD x gets wg in [x*128, (x+1)*128) = batch x.
  const int wg = ((blockIdx.x & 7) << 7) | (blockIdx.x >> 3);
  const int b = wg >> 7;                  // 128 strips per batch
  const int i0 = (wg & 127) << 5;         // 32-row strip
  const int mcol = lane & 31;
  const int half = lane >> 5;             // 0..1 (k-half)

  __shared__ float Dld[2][32 * 256];      // double-buffered, col-swizzled

  // this wave's D-column within the 256-wide tile, and its swizzled offset
  const int dcol = (w << 5) + mcol;
  const int dswz = ((dcol & 63) << 2) | (dcol >> 6);

  // A fragments: 3 splits x 4 c-chunks, lane-contiguous loads (same strip for
  // all 8 waves; L1-resident after first wave)
  const size_t atile = ((size_t)wg) * 2048;  // tile = b*128 + strip
  bf16x8 Ah[4], Al[4], Aq[4];
#pragma unroll
  for (int cc = 0; cc < 4; ++cc) {
    const size_t off = atile + (cc << 9) + (lane << 3);
    Ah[cc] = *(const bf16x8*)(xfh + off);
    Al[cc] = *(const bf16x8*)(xfl + off);
    Aq[cc] = *(const bf16x8*)(xfq + off);
  }

  float bv[4], T[4];
  int bi[4];
#pragma unroll
  for (int r = 0; r < 4; ++r) {
    bv[r] = __builtin_inff();
    T[r] = __builtin_inff();
    bi[r] = 0;
  }

  const float* xxb = xx + (b << 12);

  for (int t = 0; t < 16; ++t) {
    const int jb = t << 8;                // 256 j per iteration
    float* Db = Dld[t & 1];
    // this wave's 32-j tile: tile index (b*128 + t*8 + w)
    const size_t btile = ((size_t)((b << 7) + (t << 3) + w)) * 2048;
    f32x16 acc;
#pragma unroll
    for (int q = 0; q < 16; ++q) acc[q] = 0.f;
#pragma unroll
    for (int cc = 0; cc < 4; ++cc) {
      const size_t off = btile + (cc << 9) + (lane << 3);
      bf16x8 Bh = *(const bf16x8*)(xfh + off);
      bf16x8 Bl = *(const bf16x8*)(xfl + off);
      bf16x8 Bq = *(const bf16x8*)(xfq + off);
      acc = __builtin_amdgcn_mfma_f32_32x32x16_bf16(Ah[cc], Bh, acc, 0, 0, 0);
      acc = __builtin_amdgcn_mfma_f32_32x32x16_bf16(Ah[cc], Bl, acc, 0, 0, 0);
      acc = __builtin_amdgcn_mfma_f32_32x32x16_bf16(Al[cc], Bh, acc, 0, 0, 0);
      acc = __builtin_amdgcn_mfma_f32_32x32x16_bf16(Ah[cc], Bq, acc, 0, 0, 0);
      acc = __builtin_amdgcn_mfma_f32_32x32x16_bf16(Aq[cc], Bh, acc, 0, 0, 0);
      acc = __builtin_amdgcn_mfma_f32_32x32x16_bf16(Al[cc], Bl, acc, 0, 0, 0);
    }
    const float xxv = xxb[jb + dcol];
#pragma unroll
    for (int q = 0; q < 16; ++q) {
      int row = (q & 3) + ((q >> 2) << 3) + (half << 2);  // verified C layout
      Db[(row << 8) + dswz] = fmaf(-2.f, acc[q], xxv);
    }
    __syncthreads();

    // selection: wave owns rows w*4 .. w*4+3; one b128 read covers all 256 j
    // (sub s holds j = jb + s*64 + lane); processing order identical to v21.
#pragma unroll
    for (int r = 0; r < 4; ++r) {
      const int row = (w << 2) + r;
      const f32x4 vv = *(const f32x4*)&Db[(row << 8) + (lane << 2)];
#pragma unroll
      for (int s = 0; s < 4; ++s) {
        const float v = vv[s];
        const int jseg = jb + (s << 6);
        if (T[r] == __builtin_inff()) {
          // fill phase: exact v17 live-T loop (first sub of first tile)
          const int jlane = jseg + lane;
          unsigned long long rem = 0xFFFFFFFFFFFFFFFFull;
          while (true) {
            unsigned long long m = __ballot(v < T[r]) & rem;
            if (!m) break;
            int src = __ffsll(m) - 1;
            rem &= ~(1ull << src);
            float cv = readlane_f(v, src);
            int cj = __builtin_amdgcn_readlane(jlane, src);
            unsigned long long le = __ballot(bv[r] <= cv) & 0xFFFFFull;
            int pos = __popcll(le);
            float pv = __shfl_up(bv[r], 1);
            int pi = __shfl_up(bi[r], 1);
            if (lane >= pos) {
              bool ins = (lane == pos);
              bv[r] = ins ? cv : pv;
              bi[r] = ins ? cj : pi;
            }
            T[r] = readlane_f(bv[r], K_ - 1);
          }
        } else {
          // steady state: ONE stale-T filter ballot, then insert-only chain
          unsigned long long m = __ballot(v < T[r]);
          if (m) {
            do {
              const int src = __ffsll(m) - 1;
              m &= m - 1;
              const float cv = readlane_f(v, src);
              const int cj = jseg + src;  // SALU, exact
              const unsigned long long le = __ballot(bv[r] <= cv) & 0xFFFFFull;
              const int pos = __popcll(le);
              const float pv = __shfl_up(bv[r], 1);
              const int pi = __shfl_up(bi[r], 1);
              if (lane >= pos) {
                const bool ins = (lane == pos);
                bv[r] = ins ? cv : pv;
                bi[r] = ins ? cj : pi;
              }
            } while (m);
            T[r] = readlane_f(bv[r], K_ - 1);  // refresh only after inserts
          }
        }
      }
    }
    // no trailing barrier: next iteration writes the OTHER Dld buffer, and a
    // wave reaches the write of buffer p again only after the next
    // mid-iteration barrier (which requires every wave to finish its reads).
  }

#pragma unroll
  for (int r = 0; r < 4; ++r) {
    if (lane < K_) idx[((b << 12) + i0 + (w << 2) + r) * K_ + lane] = bi[r];
  }
}

// stats v2: same gather as before, but additionally emits per-(row,o) max/min
// of h over the K neighbors. Since hn = s*h + t is affine and LeakyReLU is
// monotone, out only needs max_k h (s>=0) or min_k h (s<0) — bitwise equal to
// max_k act(fma(h_k,s,t)) because fma and act are monotone in h.
__global__ __launch_bounds__(256) void stats_kernel(const float* __restrict__ y,
                                                    const float* __restrict__ z,
                                                    const int* __restrict__ idx,
                                                    float* __restrict__ s1,
                                                    float* __restrict__ s2,
                                                    float* __restrict__ hmax,
                                                    float* __restrict__ hmin) {
  const int tid = threadIdx.x;
  const int o = tid & 63;
  const int r = tid >> 6;
  // XCD swizzle: 512 blocks = 8 batches x 64 row-groups; pin batch -> XCD so
  // each XCD's L2 holds one batch's 1 MB y panel for the gather.
  const int wg = ((blockIdx.x & 7) << 6) | (blockIdx.x >> 3);
  const int row0 = wg << 6;  // 64 rows per block
  float a1 = 0.f, a2 = 0.f;
  for (int rl = r; rl < 64; rl += 4) {
    const int row = row0 + rl;
    const int b = row >> 12;
    const float zv = z[(row << 6) + o];
    const int* ip = idx + row * K_;
    const float* yb = y + ((size_t)b << 18);
    float s1r = 0.f;
    float hmx = -__builtin_inff();
    float hmn = __builtin_inff();
#pragma unroll
    for (int k = 0; k < K_; ++k) {
      int j = ip[k];
      float h = yb[(j << 6) + o] + zv;
      s1r += h;
      a2 = fmaf(h, h, a2);
      hmx = fmaxf(hmx, h);
      hmn = fminf(hmn, h);
    }
    a1 += s1r;
    hmax[(row << 6) + o] = hmx;
    hmin[(row << 6) + o] = hmn;
  }
  __shared__ float r1[4][64];
  __shared__ float r2[4][64];
  r1[r][o] = a1;
  r2[r][o] = a2;
  __syncthreads();
  if (tid < 64) {
    float t1 = r1[0][tid] + r1[1][tid] + r1[2][tid] + r1[3][tid];
    float t2 = r2[0][tid] + r2[1][tid] + r2[2][tid] + r2[3][tid];
    atomicAdd(&s1[tid], t1);
    atomicAdd(&s2[tid], t2);
  }
}

// out v2: pure elementwise. Recomputes the (64-wide) BN affine from s1/s2
// inline, applies act to the pre-reduced extremum, transposes via LDS to the
// [B,O,N] layout. 16 MB in / 8 MB out.
__global__ __launch_bounds__(256) void out_kernel(const float* __restrict__ hmax,
                                                  const float* __restrict__ hmin,
                                                  const float* __restrict__ s1,
                                                  const float* __restrict__ s2,
                                                  const float* __restrict__ gamma,
                                                  const float* __restrict__ beta,
                                                  float* __restrict__ out) {
  __shared__ float til[64][65];  // [o][n_local]
  const int tid = threadIdx.x;
  const int b = blockIdx.x >> 6;
  const int n0 = (blockIdx.x & 63) << 6;
  const int o = tid & 63;
  // same ops as the old finalize_kernel (division kept for identical rounding)
  const float mean = s1[o] / (float)M_TOT;
  const float var = s2[o] / (float)M_TOT - mean * mean;
  const float inv = 1.0f / sqrtf(var + BN_EPS);
  const float s = gamma[o] * inv;
  const float t = beta[o] - mean * s;
  const float* __restrict__ hsrc = (s >= 0.f) ? hmax : hmin;

  for (int nl = tid >> 6; nl < 64; nl += 4) {
    const int row = (b << 12) + n0 + nl;
    const float h = hsrc[(row << 6) + o];
    const float hn = fmaf(h, s, t);
    til[o][nl] = hn >= 0.f ? hn : NEG * hn;
  }
  __syncthreads();
  for (int rep = 0; rep < 16; ++rep) {
    int id = rep * 256 + tid;
    int oo = id >> 6, nl = id & 63;
    out[((size_t)((b << 6) + oo) << 12) + n0 + nl] = til[oo][nl];
  }
}

extern "C" void kernel_launch(void* const* d_in, const int* in_sizes, int n_in,
                              void* d_out, int out_size, void* d_ws, size_t ws_size,
                              hipStream_t stream) {
  const float* x = (const float*)d_in[0];
  const float* W = (const float*)d_in[1];
  const float* gamma = (const float*)d_in[2];
  const float* beta = (const float*)d_in[3];
  float* ws = (float*)d_ws;
  float* y = ws;
  float* z = ws + 2097152;
  float* xx = ws + 4194304;
  int* idxp = (int*)(ws + 4227072);
  float* s1 = ws + 4882432;
  float* s2 = ws + 4882496;
  ushort_t* xfh = (ushort_t*)(ws + 4882688);
  ushort_t* xfl = (ushort_t*)(ws + 5931264);
  ushort_t* xfq = (ushort_t*)(ws + 6979840);
  float* hmax = ws + 4882688;  // overlays xfh+xfl (dead after knn)
  float* hmin = ws + 6979840;  // overlays xfq + 4 MB fresh (ends 9076992)
  float* out = (float*)d_out;

  hipMemsetAsync(s1, 0, 2 * 64 * sizeof(float), stream);

  prep_kernel<<<512, 256, 0, stream>>>(x, W, y, z, xx, xfh, xfl, xfq);
  knn_kernel<<<ROWS / 32, 512, 0, stream>>>(xfh, xfl, xfq, xx, idxp);
  stats_kernel<<<512, 256, 0, stream>>>(y, z, idxp, s1, s2, hmax, hmin);
  out_kernel<<<512, 256, 0, stream>>>(hmax, hmin, s1, s2, gamma, beta, out);
}

// Round 14
// 392.959 us; speedup vs baseline: 1.1613x; 1.0020x over previous
//
#include <hip/hip_runtime.h>
#include <hip/hip_bf16.h>

#define B_ 8
#define C_ 64
#define N_ 4096
#define K_ 20
#define O_ 64

typedef unsigned short ushort_t;
typedef __attribute__((ext_vector_type(8))) short bf16x8;
typedef __attribute__((ext_vector_type(16))) float f32x16;

constexpr float BN_EPS = 1e-5f;
constexpr float NEG = 0.2f;
constexpr int ROWS = B_ * N_;        // 32768
constexpr int M_TOT = ROWS * K_;     // 655360

__device__ __forceinline__ float readlane_f(float v, int src) {
  return __int_as_float(__builtin_amdgcn_readlane(__float_as_int(v), src));
}

// RNE float -> bf16 bits
__device__ __forceinline__ unsigned int bf16_rne(float v) {
  unsigned int u = __float_as_uint(v);
  return (u + 0x7FFFu + ((u >> 16) & 1u)) >> 16;
}

// ----------------------------------------------------------------------------
// ws layout (float elements):
//   y   : [0,        2097152)   y[b][n][o]  = xt[b,n,:] . W1[o,:]
//   z   : [2097152,  4194304)   z[b][n][o]  = xt[b,n,:] . (W2-W1)[o,:]
//   xx  : [4194304,  4227072)   xx[b][n]    = ||xt[b,n,:]||^2
//   idx : [4227072,  4882432)   (int) idx[b][n][k]
//   s1/s2 : [4882432, 4882560)
//   xfh : [4882688,  5931264)   bf16 FRAGMENT-ORDER tiles, high split
//   xfl : [5931264,  6979840)   mid split
//   xfq : [6979840,  8028416)   low split
//   hmax: [4882688,  6979840)   (overlays xfh+xfl — fragments dead after knn)
//   hmin: [6979840,  9076992)   (overlays xfq + 4 MB fresh)
// Fragment-order => MFMA A/B loads are lane-contiguous: addr = tile*2048
//   + cc*512 + lane*8 (one dwordx4 = 1 KB dense per wave).
// ----------------------------------------------------------------------------

__global__ __launch_bounds__(256) void prep_kernel(const float* __restrict__ x,
                                                   const float* __restrict__ W,
                                                   float* __restrict__ y,
                                                   float* __restrict__ z,
                                                   float* __restrict__ xx,
                                                   ushort_t* __restrict__ xfh,
                                                   ushort_t* __restrict__ xfl,
                                                   ushort_t* __restrict__ xfq) {
  __shared__ float xt[64][65];  // [n_local][c]
  __shared__ float w1[64][65];  // [o][c]   = W[o][c]
  __shared__ float wd[64][65];  // [o][c]   = W[o][64+c] - W[o][c]
  const int b = blockIdx.x >> 6;
  const int n0 = (blockIdx.x & 63) << 6;
  const int tid = threadIdx.x;

  for (int rep = 0; rep < 16; ++rep) {
    int id = rep * 256 + tid;
    int cc = id >> 6, nl = id & 63;
    xt[nl][cc] = x[((b * 64 + cc) << 12) + n0 + nl];  // coalesced over nl
    int o = cc, c = nl;
    float a = W[o * 128 + c];
    float bb = W[o * 128 + 64 + c];
    w1[o][c] = a;
    wd[o][c] = bb - a;
  }
  __syncthreads();

  const int o = tid & 63;
  for (int nl = tid >> 6; nl < 64; nl += 4) {
    float ay = 0.f, az = 0.f;
#pragma unroll 8
    for (int c = 0; c < 64; ++c) {
      float v = xt[nl][c];
      ay = fmaf(v, w1[o][c], ay);
      az = fmaf(v, wd[o][c], az);
    }
    int gi = (((b << 12) + n0 + nl) << 6) + o;
    y[gi] = ay;
    z[gi] = az;
  }
  if (tid < 64) {
    float s = 0.f;
#pragma unroll 8
    for (int c = 0; c < 64; ++c) {
      float v = xt[tid][c];
      s = fmaf(v, v, s);
    }
    xx[(b << 12) + tid + n0] = s;
  }

  // 3-way bf16 split, written in MFMA fragment order (tile/chunk/m/t)
  for (int rep = 0; rep < 16; ++rep) {
    int id = rep * 256 + tid;
    int nl = id >> 6, c = id & 63;
    float v = xt[nl][c];
    unsigned int hb = bf16_rne(v);
    float hf = __uint_as_float(hb << 16);
    float r1 = v - hf;
    unsigned int lb = bf16_rne(r1);
    float lf = __uint_as_float(lb << 16);
    unsigned int qb = bf16_rne(r1 - lf);
    const int n = n0 + nl;
    const size_t addr = ((size_t)((b << 7) + (n >> 5))) * 2048  // tile
                        + ((c >> 3) << 8)                        // chunk*256
                        + ((n & 31) << 3)                        // m*8
                        + (c & 7);                               // t
    xfh[addr] = (ushort_t)hb;
    xfl[addr] = (ushort_t)lb;
    xfq[addr] = (ushort_t)qb;
  }
}

// knn v31 = v21 (verified best, knn=291us) + ONLY v30's part (b):
// GUARDED T-refresh. v30's part (a) (col-swizzled b128 reads) is reverted —
// R13 counters showed it introduced an 8-way WRITE bank conflict (12.6M
// SQ_LDS_BANK_CONFLICT, ~2.9x on the 16 epilogue stores) that cancelled the
// read savings (knn 296 vs 291). v21's layout is conflict-free on both sides.
// The guard: T can only change after an insert, so the trailing readlane is
// skipped when the segment's filter mask is empty (~60-70% of late segments)
// — an exact serial-round-trip removal, the same mechanism as R7's win.
// Everything else byte-identical to v21.
__global__ __launch_bounds__(512, 2) void knn_kernel(const ushort_t* __restrict__ xfh,
                                                     const ushort_t* __restrict__ xfl,
                                                     const ushort_t* __restrict__ xfq,
                                                     const float* __restrict__ xx,
                                                     int* __restrict__ idx) {
  const int tid = threadIdx.x;
  const int w = tid >> 6;                 // wave 0..7
  const int lane = tid & 63;
  // XCD swizzle: 1024 blocks = 8 batches x 128 strips; hw round-robins
  // blockIdx%8 -> XCD, so XCD x gets wg in [x*128, (x+1)*128) = batch x.
  const int wg = ((blockIdx.x & 7) << 7) | (blockIdx.x >> 3);
  const int b = wg >> 7;                  // 128 strips per batch
  const int i0 = (wg & 127) << 5;         // 32-row strip
  const int mcol = lane & 31;
  const int half = lane >> 5;             // 0..1 (k-half)

  __shared__ float Dld[2][32 * 256];      // double-buffered [row][256 j]

  // A fragments: 3 splits x 4 c-chunks, lane-contiguous loads (same strip for
  // all 8 waves; L1-resident after first wave)
  const size_t atile = ((size_t)wg) * 2048;  // tile = b*128 + strip
  bf16x8 Ah[4], Al[4], Aq[4];
#pragma unroll
  for (int cc = 0; cc < 4; ++cc) {
    const size_t off = atile + (cc << 9) + (lane << 3);
    Ah[cc] = *(const bf16x8*)(xfh + off);
    Al[cc] = *(const bf16x8*)(xfl + off);
    Aq[cc] = *(const bf16x8*)(xfq + off);
  }

  float bv[4], T[4];
  int bi[4];
#pragma unroll
  for (int r = 0; r < 4; ++r) {
    bv[r] = __builtin_inff();
    T[r] = __builtin_inff();
    bi[r] = 0;
  }

  const float* xxb = xx + (b << 12);

  for (int t = 0; t < 16; ++t) {
    const int jb = t << 8;                // 256 j per iteration
    float* Db = Dld[t & 1];
    // this wave's 32-j tile: tile index (b*128 + t*8 + w)
    const size_t btile = ((size_t)((b << 7) + (t << 3) + w)) * 2048;
    f32x16 acc;
#pragma unroll
    for (int q = 0; q < 16; ++q) acc[q] = 0.f;
#pragma unroll
    for (int cc = 0; cc < 4; ++cc) {
      const size_t off = btile + (cc << 9) + (lane << 3);
      bf16x8 Bh = *(const bf16x8*)(xfh + off);
      bf16x8 Bl = *(const bf16x8*)(xfl + off);
      bf16x8 Bq = *(const bf16x8*)(xfq + off);
      acc = __builtin_amdgcn_mfma_f32_32x32x16_bf16(Ah[cc], Bh, acc, 0, 0, 0);
      acc = __builtin_amdgcn_mfma_f32_32x32x16_bf16(Ah[cc], Bl, acc, 0, 0, 0);
      acc = __builtin_amdgcn_mfma_f32_32x32x16_bf16(Al[cc], Bh, acc, 0, 0, 0);
      acc = __builtin_amdgcn_mfma_f32_32x32x16_bf16(Ah[cc], Bq, acc, 0, 0, 0);
      acc = __builtin_amdgcn_mfma_f32_32x32x16_bf16(Aq[cc], Bh, acc, 0, 0, 0);
      acc = __builtin_amdgcn_mfma_f32_32x32x16_bf16(Al[cc], Bl, acc, 0, 0, 0);
    }
    const float xxv = xxb[jb + (w << 5) + mcol];
#pragma unroll
    for (int q = 0; q < 16; ++q) {
      int row = (q & 3) + ((q >> 2) << 3) + (half << 2);  // verified C layout
      Db[(row << 8) + (w << 5) + mcol] = fmaf(-2.f, acc[q], xxv);
    }
    __syncthreads();

    // selection: wave owns rows w*4 .. w*4+3, scans 256 j in four 64-lane segs
#pragma unroll
    for (int r = 0; r < 4; ++r) {
      const int row = (w << 2) + r;
#pragma unroll
      for (int seg = 0; seg < 4; ++seg) {
        float v = Db[(row << 8) + (seg << 6) + lane];
        const int jseg = jb + (seg << 6);
        if (T[r] == __builtin_inff()) {
          // fill phase: exact v17 live-T loop (first segment of each row)
          const int jlane = jseg + lane;
          unsigned long long rem = 0xFFFFFFFFFFFFFFFFull;
          while (true) {
            unsigned long long m = __ballot(v < T[r]) & rem;
            if (!m) break;
            int src = __ffsll(m) - 1;
            rem &= ~(1ull << src);
            float cv = readlane_f(v, src);
            int cj = __builtin_amdgcn_readlane(jlane, src);
            unsigned long long le = __ballot(bv[r] <= cv) & 0xFFFFFull;
            int pos = __popcll(le);
            float pv = __shfl_up(bv[r], 1);
            int pi = __shfl_up(bi[r], 1);
            if (lane >= pos) {
              bool ins = (lane == pos);
              bv[r] = ins ? cv : pv;
              bi[r] = ins ? cj : pi;
            }
            T[r] = readlane_f(bv[r], K_ - 1);
          }
        } else {
          // steady state: ONE stale-T filter ballot, then insert-only chain;
          // T refreshed only when an insert actually happened (exact).
          unsigned long long m = __ballot(v < T[r]);
          if (m) {
            do {
              const int src = __ffsll(m) - 1;
              m &= m - 1;
              const float cv = readlane_f(v, src);
              const int cj = jseg + src;  // SALU, exact
              const unsigned long long le = __ballot(bv[r] <= cv) & 0xFFFFFull;
              const int pos = __popcll(le);
              const float pv = __shfl_up(bv[r], 1);
              const int pi = __shfl_up(bi[r], 1);
              if (lane >= pos) {
                const bool ins = (lane == pos);
                bv[r] = ins ? cv : pv;
                bi[r] = ins ? cj : pi;
              }
            } while (m);
            T[r] = readlane_f(bv[r], K_ - 1);
          }
        }
      }
    }
    // no trailing barrier: next iteration writes the OTHER Dld buffer, and a
    // wave reaches the write of buffer p again only after the next
    // mid-iteration barrier (which requires every wave to finish its reads).
  }

#pragma unroll
  for (int r = 0; r < 4; ++r) {
    if (lane < K_) idx[((b << 12) + i0 + (w << 2) + r) * K_ + lane] = bi[r];
  }
}

// stats v2: same gather as before, but additionally emits per-(row,o) max/min
// of h over the K neighbors. Since hn = s*h + t is affine and LeakyReLU is
// monotone, out only needs max_k h (s>=0) or min_k h (s<0) — bitwise equal to
// max_k act(fma(h_k,s,t)) because fma and act are monotone in h.
__global__ __launch_bounds__(256) void stats_kernel(const float* __restrict__ y,
                                                    const float* __restrict__ z,
                                                    const int* __restrict__ idx,
                                                    float* __restrict__ s1,
                                                    float* __restrict__ s2,
                                                    float* __restrict__ hmax,
                                                    float* __restrict__ hmin) {
  const int tid = threadIdx.x;
  const int o = tid & 63;
  const int r = tid >> 6;
  // XCD swizzle: 512 blocks = 8 batches x 64 row-groups; pin batch -> XCD so
  // each XCD's L2 holds one batch's 1 MB y panel for the gather.
  const int wg = ((blockIdx.x & 7) << 6) | (blockIdx.x >> 3);
  const int row0 = wg << 6;  // 64 rows per block
  float a1 = 0.f, a2 = 0.f;
  for (int rl = r; rl < 64; rl += 4) {
    const int row = row0 + rl;
    const int b = row >> 12;
    const float zv = z[(row << 6) + o];
    const int* ip = idx + row * K_;
    const float* yb = y + ((size_t)b << 18);
    float s1r = 0.f;
    float hmx = -__builtin_inff();
    float hmn = __builtin_inff();
#pragma unroll
    for (int k = 0; k < K_; ++k) {
      int j = ip[k];
      float h = yb[(j << 6) + o] + zv;
      s1r += h;
      a2 = fmaf(h, h, a2);
      hmx = fmaxf(hmx, h);
      hmn = fminf(hmn, h);
    }
    a1 += s1r;
    hmax[(row << 6) + o] = hmx;
    hmin[(row << 6) + o] = hmn;
  }
  __shared__ float r1[4][64];
  __shared__ float r2[4][64];
  r1[r][o] = a1;
  r2[r][o] = a2;
  __syncthreads();
  if (tid < 64) {
    float t1 = r1[0][tid] + r1[1][tid] + r1[2][tid] + r1[3][tid];
    float t2 = r2[0][tid] + r2[1][tid] + r2[2][tid] + r2[3][tid];
    atomicAdd(&s1[tid], t1);
    atomicAdd(&s2[tid], t2);
  }
}

// out v2: pure elementwise. Recomputes the (64-wide) BN affine from s1/s2
// inline, applies act to the pre-reduced extremum, transposes via LDS to the
// [B,O,N] layout. 16 MB in / 8 MB out.
__global__ __launch_bounds__(256) void out_kernel(const float* __restrict__ hmax,
                                                  const float* __restrict__ hmin,
                                                  const float* __restrict__ s1,
                                                  const float* __restrict__ s2,
                                                  const float* __restrict__ gamma,
                                                  const float* __restrict__ beta,
                                                  float* __restrict__ out) {
  __shared__ float til[64][65];  // [o][n_local]
  const int tid = threadIdx.x;
  const int b = blockIdx.x >> 6;
  const int n0 = (blockIdx.x & 63) << 6;
  const int o = tid & 63;
  // same ops as the old finalize_kernel (division kept for identical rounding)
  const float mean = s1[o] / (float)M_TOT;
  const float var = s2[o] / (float)M_TOT - mean * mean;
  const float inv = 1.0f / sqrtf(var + BN_EPS);
  const float s = gamma[o] * inv;
  const float t = beta[o] - mean * s;
  const float* __restrict__ hsrc = (s >= 0.f) ? hmax : hmin;

  for (int nl = tid >> 6; nl < 64; nl += 4) {
    const int row = (b << 12) + n0 + nl;
    const float h = hsrc[(row << 6) + o];
    const float hn = fmaf(h, s, t);
    til[o][nl] = hn >= 0.f ? hn : NEG * hn;
  }
  __syncthreads();
  for (int rep = 0; rep < 16; ++rep) {
    int id = rep * 256 + tid;
    int oo = id >> 6, nl = id & 63;
    out[((size_t)((b << 6) + oo) << 12) + n0 + nl] = til[oo][nl];
  }
}

extern "C" void kernel_launch(void* const* d_in, const int* in_sizes, int n_in,
                              void* d_out, int out_size, void* d_ws, size_t ws_size,
                              hipStream_t stream) {
  const float* x = (const float*)d_in[0];
  const float* W = (const float*)d_in[1];
  const float* gamma = (const float*)d_in[2];
  const float* beta = (const float*)d_in[3];
  float* ws = (float*)d_ws;
  float* y = ws;
  float* z = ws + 2097152;
  float* xx = ws + 4194304;
  int* idxp = (int*)(ws + 4227072);
  float* s1 = ws + 4882432;
  float* s2 = ws + 4882496;
  ushort_t* xfh = (ushort_t*)(ws + 4882688);
  ushort_t* xfl = (ushort_t*)(ws + 5931264);
  ushort_t* xfq = (ushort_t*)(ws + 6979840);
  float* hmax = ws + 4882688;  // overlays xfh+xfl (dead after knn)
  float* hmin = ws + 6979840;  // overlays xfq + 4 MB fresh (ends 9076992)
  float* out = (float*)d_out;

  hipMemsetAsync(s1, 0, 2 * 64 * sizeof(float), stream);

  prep_kernel<<<512, 256, 0, stream>>>(x, W, y, z, xx, xfh, xfl, xfq);
  knn_kernel<<<ROWS / 32, 512, 0, stream>>>(xfh, xfl, xfq, xx, idxp);
  stats_kernel<<<512, 256, 0, stream>>>(y, z, idxp, s1, s2, hmax, hmin);
  out_kernel<<<512, 256, 0, stream>>>(hmax, hmin, s1, s2, gamma, beta, out);
}

// Round 15
// 391.594 us; speedup vs baseline: 1.1654x; 1.0035x over previous
//
#include <hip/hip_runtime.h>
#include <hip/hip_bf16.h>

#define B_ 8
#define C_ 64
#define N_ 4096
#define K_ 20
#define O_ 64

typedef unsigned short ushort_t;
typedef __attribute__((ext_vector_type(8))) short bf16x8;
typedef __attribute__((ext_vector_type(16))) float f32x16;

constexpr float BN_EPS = 1e-5f;
constexpr float NEG = 0.2f;
constexpr int ROWS = B_ * N_;        // 32768
constexpr int M_TOT = ROWS * K_;     // 655360

__device__ __forceinline__ float readlane_f(float v, int src) {
  return __int_as_float(__builtin_amdgcn_readlane(__float_as_int(v), src));
}

// RNE float -> bf16 bits
__device__ __forceinline__ unsigned int bf16_rne(float v) {
  unsigned int u = __float_as_uint(v);
  return (u + 0x7FFFu + ((u >> 16) & 1u)) >> 16;
}

// ----------------------------------------------------------------------------
// ws layout (float elements):
//   y   : [0,        2097152)   y[b][n][o]  = xt[b,n,:] . W1[o,:]
//   z   : [2097152,  4194304)   z[b][n][o]  = xt[b,n,:] . (W2-W1)[o,:]
//   xx  : [4194304,  4227072)   xx[b][n]    = ||xt[b,n,:]||^2
//   idx : [4227072,  4882432)   (int) idx[b][n][k]
//   s1/s2 : [4882432, 4882560)
//   xfh : [4882688,  5931264)   bf16 FRAGMENT-ORDER tiles, high split
//   xfl : [5931264,  6979840)   mid split
//   xfq : [6979840,  8028416)   low split
//   hmax: [4882688,  6979840)   (overlays xfh+xfl — fragments dead after knn)
//   hmin: [6979840,  9076992)   (overlays xfq + 4 MB fresh)
// Fragment-order => MFMA A/B loads are lane-contiguous: addr = tile*2048
//   + cc*512 + lane*8 (one dwordx4 = 1 KB dense per wave).
// ----------------------------------------------------------------------------

__global__ __launch_bounds__(256) void prep_kernel(const float* __restrict__ x,
                                                   const float* __restrict__ W,
                                                   float* __restrict__ y,
                                                   float* __restrict__ z,
                                                   float* __restrict__ xx,
                                                   ushort_t* __restrict__ xfh,
                                                   ushort_t* __restrict__ xfl,
                                                   ushort_t* __restrict__ xfq) {
  __shared__ float xt[64][65];  // [n_local][c]
  __shared__ float w1[64][65];  // [o][c]   = W[o][c]
  __shared__ float wd[64][65];  // [o][c]   = W[o][64+c] - W[o][c]
  const int b = blockIdx.x >> 6;
  const int n0 = (blockIdx.x & 63) << 6;
  const int tid = threadIdx.x;

  for (int rep = 0; rep < 16; ++rep) {
    int id = rep * 256 + tid;
    int cc = id >> 6, nl = id & 63;
    xt[nl][cc] = x[((b * 64 + cc) << 12) + n0 + nl];  // coalesced over nl
    int o = cc, c = nl;
    float a = W[o * 128 + c];
    float bb = W[o * 128 + 64 + c];
    w1[o][c] = a;
    wd[o][c] = bb - a;
  }
  __syncthreads();

  const int o = tid & 63;
  for (int nl = tid >> 6; nl < 64; nl += 4) {
    float ay = 0.f, az = 0.f;
#pragma unroll 8
    for (int c = 0; c < 64; ++c) {
      float v = xt[nl][c];
      ay = fmaf(v, w1[o][c], ay);
      az = fmaf(v, wd[o][c], az);
    }
    int gi = (((b << 12) + n0 + nl) << 6) + o;
    y[gi] = ay;
    z[gi] = az;
  }
  if (tid < 64) {
    float s = 0.f;
#pragma unroll 8
    for (int c = 0; c < 64; ++c) {
      float v = xt[tid][c];
      s = fmaf(v, v, s);
    }
    xx[(b << 12) + tid + n0] = s;
  }

  // 3-way bf16 split, written in MFMA fragment order (tile/chunk/m/t)
  for (int rep = 0; rep < 16; ++rep) {
    int id = rep * 256 + tid;
    int nl = id >> 6, c = id & 63;
    float v = xt[nl][c];
    unsigned int hb = bf16_rne(v);
    float hf = __uint_as_float(hb << 16);
    float r1 = v - hf;
    unsigned int lb = bf16_rne(r1);
    float lf = __uint_as_float(lb << 16);
    unsigned int qb = bf16_rne(r1 - lf);
    const int n = n0 + nl;
    const size_t addr = ((size_t)((b << 7) + (n >> 5))) * 2048  // tile
                        + ((c >> 3) << 8)                        // chunk*256
                        + ((n & 31) << 3)                        // m*8
                        + (c & 7);                               // t
    xfh[addr] = (ushort_t)hb;
    xfl[addr] = (ushort_t)lb;
    xfq[addr] = (ushort_t)qb;
  }
}

// knn v21 — FINAL (reverted to the best-measured config: knn=291us, total
// 391.8us @ R7). History: 9 selection-chain formulations tried across
// R3-R14; only the stale-T filter (this version) won. Occupancy axis closed
// (R9-R11: 64-reg quantum unreachable, 4 waves/SIMD is the max for ~76 regs).
// R14 showed even guarding the per-segment T-readlane costs ~4us (branch
// machinery > readlane). Structure: 512 thr / 8 waves, 16 tiles x 256 j,
// 64 KiB double-buffered Dld, no trailing barrier, XCD swizzle.
//  - Filter ballot(v<T) once per segment with stale T (exact: T is
//    non-increasing; extras have cv >= bv[19] -> land past lane 19: no-op).
//  - Fill phase (T==inf) keeps the live-T loop.
//  - cj = jseg + src (SALU; jlane affine in lane).
__global__ __launch_bounds__(512, 2) void knn_kernel(const ushort_t* __restrict__ xfh,
                                                     const ushort_t* __restrict__ xfl,
                                                     const ushort_t* __restrict__ xfq,
                                                     const float* __restrict__ xx,
                                                     int* __restrict__ idx) {
  const int tid = threadIdx.x;
  const int w = tid >> 6;                 // wave 0..7
  const int lane = tid & 63;
  // XCD swizzle: 1024 blocks = 8 batches x 128 strips; hw round-robins
  // blockIdx%8 -> XCD, so XCD x gets wg in [x*128, (x+1)*128) = batch x.
  const int wg = ((blockIdx.x & 7) << 7) | (blockIdx.x >> 3);
  const int b = wg >> 7;                  // 128 strips per batch
  const int i0 = (wg & 127) << 5;         // 32-row strip
  const int mcol = lane & 31;
  const int half = lane >> 5;             // 0..1 (k-half)

  __shared__ float Dld[2][32 * 256];      // double-buffered [row][256 j]

  // A fragments: 3 splits x 4 c-chunks, lane-contiguous loads (same strip for
  // all 8 waves; L1-resident after first wave)
  const size_t atile = ((size_t)wg) * 2048;  // tile = b*128 + strip
  bf16x8 Ah[4], Al[4], Aq[4];
#pragma unroll
  for (int cc = 0; cc < 4; ++cc) {
    const size_t off = atile + (cc << 9) + (lane << 3);
    Ah[cc] = *(const bf16x8*)(xfh + off);
    Al[cc] = *(const bf16x8*)(xfl + off);
    Aq[cc] = *(const bf16x8*)(xfq + off);
  }

  float bv[4], T[4];
  int bi[4];
#pragma unroll
  for (int r = 0; r < 4; ++r) {
    bv[r] = __builtin_inff();
    T[r] = __builtin_inff();
    bi[r] = 0;
  }

  const float* xxb = xx + (b << 12);

  for (int t = 0; t < 16; ++t) {
    const int jb = t << 8;                // 256 j per iteration
    float* Db = Dld[t & 1];
    // this wave's 32-j tile: tile index (b*128 + t*8 + w)
    const size_t btile = ((size_t)((b << 7) + (t << 3) + w)) * 2048;
    f32x16 acc;
#pragma unroll
    for (int q = 0; q < 16; ++q) acc[q] = 0.f;
#pragma unroll
    for (int cc = 0; cc < 4; ++cc) {
      const size_t off = btile + (cc << 9) + (lane << 3);
      bf16x8 Bh = *(const bf16x8*)(xfh + off);
      bf16x8 Bl = *(const bf16x8*)(xfl + off);
      bf16x8 Bq = *(const bf16x8*)(xfq + off);
      acc = __builtin_amdgcn_mfma_f32_32x32x16_bf16(Ah[cc], Bh, acc, 0, 0, 0);
      acc = __builtin_amdgcn_mfma_f32_32x32x16_bf16(Ah[cc], Bl, acc, 0, 0, 0);
      acc = __builtin_amdgcn_mfma_f32_32x32x16_bf16(Al[cc], Bh, acc, 0, 0, 0);
      acc = __builtin_amdgcn_mfma_f32_32x32x16_bf16(Ah[cc], Bq, acc, 0, 0, 0);
      acc = __builtin_amdgcn_mfma_f32_32x32x16_bf16(Aq[cc], Bh, acc, 0, 0, 0);
      acc = __builtin_amdgcn_mfma_f32_32x32x16_bf16(Al[cc], Bl, acc, 0, 0, 0);
    }
    const float xxv = xxb[jb + (w << 5) + mcol];
#pragma unroll
    for (int q = 0; q < 16; ++q) {
      int row = (q & 3) + ((q >> 2) << 3) + (half << 2);  // verified C layout
      Db[(row << 8) + (w << 5) + mcol] = fmaf(-2.f, acc[q], xxv);
    }
    __syncthreads();

    // selection: wave owns rows w*4 .. w*4+3, scans 256 j in four 64-lane segs
#pragma unroll
    for (int r = 0; r < 4; ++r) {
      const int row = (w << 2) + r;
#pragma unroll
      for (int seg = 0; seg < 4; ++seg) {
        float v = Db[(row << 8) + (seg << 6) + lane];
        const int jseg = jb + (seg << 6);
        if (T[r] == __builtin_inff()) {
          // fill phase: exact v17 live-T loop (first segment of each row)
          const int jlane = jseg + lane;
          unsigned long long rem = 0xFFFFFFFFFFFFFFFFull;
          while (true) {
            unsigned long long m = __ballot(v < T[r]) & rem;
            if (!m) break;
            int src = __ffsll(m) - 1;
            rem &= ~(1ull << src);
            float cv = readlane_f(v, src);
            int cj = __builtin_amdgcn_readlane(jlane, src);
            unsigned long long le = __ballot(bv[r] <= cv) & 0xFFFFFull;
            int pos = __popcll(le);
            float pv = __shfl_up(bv[r], 1);
            int pi = __shfl_up(bi[r], 1);
            if (lane >= pos) {
              bool ins = (lane == pos);
              bv[r] = ins ? cv : pv;
              bi[r] = ins ? cj : pi;
            }
            T[r] = readlane_f(bv[r], K_ - 1);
          }
        } else {
          // steady state: ONE stale-T filter ballot, then insert-only chain
          unsigned long long m = __ballot(v < T[r]);
          while (m) {
            const int src = __ffsll(m) - 1;
            m &= m - 1;
            const float cv = readlane_f(v, src);
            const int cj = jseg + src;  // SALU, exact
            const unsigned long long le = __ballot(bv[r] <= cv) & 0xFFFFFull;
            const int pos = __popcll(le);
            const float pv = __shfl_up(bv[r], 1);
            const int pi = __shfl_up(bi[r], 1);
            if (lane >= pos) {
              const bool ins = (lane == pos);
              bv[r] = ins ? cv : pv;
              bi[r] = ins ? cj : pi;
            }
          }
          T[r] = readlane_f(bv[r], K_ - 1);  // refresh once per segment
        }
      }
    }
    // no trailing barrier: next iteration writes the OTHER Dld buffer, and a
    // wave reaches the write of buffer p again only after the next
    // mid-iteration barrier (which requires every wave to finish its reads).
  }

#pragma unroll
  for (int r = 0; r < 4; ++r) {
    if (lane < K_) idx[((b << 12) + i0 + (w << 2) + r) * K_ + lane] = bi[r];
  }
}

// stats v2: same gather as before, but additionally emits per-(row,o) max/min
// of h over the K neighbors. Since hn = s*h + t is affine and LeakyReLU is
// monotone, out only needs max_k h (s>=0) or min_k h (s<0) — bitwise equal to
// max_k act(fma(h_k,s,t)) because fma and act are monotone in h.
__global__ __launch_bounds__(256) void stats_kernel(const float* __restrict__ y,
                                                    const float* __restrict__ z,
                                                    const int* __restrict__ idx,
                                                    float* __restrict__ s1,
                                                    float* __restrict__ s2,
                                                    float* __restrict__ hmax,
                                                    float* __restrict__ hmin) {
  const int tid = threadIdx.x;
  const int o = tid & 63;
  const int r = tid >> 6;
  // XCD swizzle: 512 blocks = 8 batches x 64 row-groups; pin batch -> XCD so
  // each XCD's L2 holds one batch's 1 MB y panel for the gather.
  const int wg = ((blockIdx.x & 7) << 6) | (blockIdx.x >> 3);
  const int row0 = wg << 6;  // 64 rows per block
  float a1 = 0.f, a2 = 0.f;
  for (int rl = r; rl < 64; rl += 4) {
    const int row = row0 + rl;
    const int b = row >> 12;
    const float zv = z[(row << 6) + o];
    const int* ip = idx + row * K_;
    const float* yb = y + ((size_t)b << 18);
    float s1r = 0.f;
    float hmx = -__builtin_inff();
    float hmn = __builtin_inff();
#pragma unroll
    for (int k = 0; k < K_; ++k) {
      int j = ip[k];
      float h = yb[(j << 6) + o] + zv;
      s1r += h;
      a2 = fmaf(h, h, a2);
      hmx = fmaxf(hmx, h);
      hmn = fminf(hmn, h);
    }
    a1 += s1r;
    hmax[(row << 6) + o] = hmx;
    hmin[(row << 6) + o] = hmn;
  }
  __shared__ float r1[4][64];
  __shared__ float r2[4][64];
  r1[r][o] = a1;
  r2[r][o] = a2;
  __syncthreads();
  if (tid < 64) {
    float t1 = r1[0][tid] + r1[1][tid] + r1[2][tid] + r1[3][tid];
    float t2 = r2[0][tid] + r2[1][tid] + r2[2][tid] + r2[3][tid];
    atomicAdd(&s1[tid], t1);
    atomicAdd(&s2[tid], t2);
  }
}

// out v2: pure elementwise. Recomputes the (64-wide) BN affine from s1/s2
// inline, applies act to the pre-reduced extremum, transposes via LDS to the
// [B,O,N] layout. 16 MB in / 8 MB out.
__global__ __launch_bounds__(256) void out_kernel(const float* __restrict__ hmax,
                                                  const float* __restrict__ hmin,
                                                  const float* __restrict__ s1,
                                                  const float* __restrict__ s2,
                                                  const float* __restrict__ gamma,
                                                  const float* __restrict__ beta,
                                                  float* __restrict__ out) {
  __shared__ float til[64][65];  // [o][n_local]
  const int tid = threadIdx.x;
  const int b = blockIdx.x >> 6;
  const int n0 = (blockIdx.x & 63) << 6;
  const int o = tid & 63;
  // same ops as the old finalize_kernel (division kept for identical rounding)
  const float mean = s1[o] / (float)M_TOT;
  const float var = s2[o] / (float)M_TOT - mean * mean;
  const float inv = 1.0f / sqrtf(var + BN_EPS);
  const float s = gamma[o] * inv;
  const float t = beta[o] - mean * s;
  const float* __restrict__ hsrc = (s >= 0.f) ? hmax : hmin;

  for (int nl = tid >> 6; nl < 64; nl += 4) {
    const int row = (b << 12) + n0 + nl;
    const float h = hsrc[(row << 6) + o];
    const float hn = fmaf(h, s, t);
    til[o][nl] = hn >= 0.f ? hn : NEG * hn;
  }
  __syncthreads();
  for (int rep = 0; rep < 16; ++rep) {
    int id = rep * 256 + tid;
    int oo = id >> 6, nl = id & 63;
    out[((size_t)((b << 6) + oo) << 12) + n0 + nl] = til[oo][nl];
  }
}

extern "C" void kernel_launch(void* const* d_in, const int* in_sizes, int n_in,
                              void* d_out, int out_size, void* d_ws, size_t ws_size,
                              hipStream_t stream) {
  const float* x = (const float*)d_in[0];
  const float* W = (const float*)d_in[1];
  const float* gamma = (const float*)d_in[2];
  const float* beta = (const float*)d_in[3];
  float* ws = (float*)d_ws;
  float* y = ws;
  float* z = ws + 2097152;
  float* xx = ws + 4194304;
  int* idxp = (int*)(ws + 4227072);
  float* s1 = ws + 4882432;
  float* s2 = ws + 4882496;
  ushort_t* xfh = (ushort_t*)(ws + 4882688);
  ushort_t* xfl = (ushort_t*)(ws + 5931264);
  ushort_t* xfq = (ushort_t*)(ws + 6979840);
  float* hmax = ws + 4882688;  // overlays xfh+xfl (dead after knn)
  float* hmin = ws + 6979840;  // overlays xfq + 4 MB fresh (ends 9076992)
  float* out = (float*)d_out;

  hipMemsetAsync(s1, 0, 2 * 64 * sizeof(float), stream);

  prep_kernel<<<512, 256, 0, stream>>>(x, W, y, z, xx, xfh, xfl, xfq);
  knn_kernel<<<ROWS / 32, 512, 0, stream>>>(xfh, xfl, xfq, xx, idxp);
  stats_kernel<<<512, 256, 0, stream>>>(y, z, idxp, s1, s2, hmax, hmin);
  out_kernel<<<512, 256, 0, stream>>>(hmax, hmin, s1, s2, gamma, beta, out);
}